// Round 10
// baseline (385.675 us; speedup 1.0000x reference)
//
#include <hip/hip_runtime.h>

#define N_NODES 50000
#define N_EDGES 800000

typedef __attribute__((ext_vector_type(8))) short short8;
typedef __attribute__((ext_vector_type(4))) float floatx4;

__device__ __forceinline__ short f2bf(float f) {
  unsigned int u = __builtin_bit_cast(unsigned int, f);
  unsigned int r = (u + 0x7FFFu + ((u >> 16) & 1u)) >> 16;
  return (short)r;
}
// pack two f32 -> packed bf16 dword, round-to-nearest (+0x8000)
__device__ __forceinline__ unsigned int pack2bf(float a, float b) {
  unsigned int ua = __builtin_bit_cast(unsigned int, a);
  unsigned int ub = __builtin_bit_cast(unsigned int, b);
  return ((ua + 0x8000u) >> 16) | ((ub + 0x8000u) & 0xFFFF0000u);
}
__device__ __forceinline__ float bflo2f(unsigned int u) {
  return __builtin_bit_cast(float, u << 16);
}
__device__ __forceinline__ float bfhi2f(unsigned int u) {
  return __builtin_bit_cast(float, u & 0xFFFF0000u);
}
__device__ __forceinline__ float fsilu(float v) {
  float e = __builtin_amdgcn_exp2f(v * -1.442695041f);
  return v * __builtin_amdgcn_rcpf(1.f + e);
}

// f32 weights [K,128] -> bf16 MFMA frag order (doubles as A-frag of W^T)
__global__ void prep_weights(const float* __restrict__ eW1, const float* __restrict__ eW2,
                             const float* __restrict__ nW1, const float* __restrict__ nW2,
                             short* __restrict__ W1f, short* __restrict__ W2f,
                             short* __restrict__ N1f, short* __restrict__ N2f) {
  int id = blockIdx.x * 256 + threadIdx.x;   // 0..12287
  const float* src; short* dst; int ch;
  if (id < 4096)       { src = eW1; dst = W1f; ch = id; }
  else if (id < 6144)  { src = eW2; dst = W2f; ch = id - 4096; }
  else if (id < 10240) { src = nW1; dst = N1f; ch = id - 6144; }
  else                 { src = nW2; dst = N2f; ch = id - 10240; }
  int kt = ch >> 9;
  int c  = (ch >> 6) & 7;
  int l  = ch & 63;
  int q = l >> 4, n = l & 15;
  int k0 = kt * 32 + q * 8;
  int col = c * 16 + n;
  short tmp[8];
#pragma unroll
  for (int j = 0; j < 8; ++j) tmp[j] = f2bf(src[(k0 + j) * 128 + col]);
#pragma unroll
  for (int j = 0; j < 8; ++j) dst[ch * 8 + j] = tmp[j];
}

// Per-node layer-1 split: R' = h @ eW1_top + eb1,  S = h @ eW1_bot (both bf16).
__global__ void __launch_bounds__(512, 6) prep_hR(
    const float* __restrict__ h, const short* __restrict__ W1f,
    const float* __restrict__ eb1,
    short* __restrict__ Rb, short* __restrict__ Sb) {
  __shared__ __align__(16) short Z[64 * 136];
  const int tid = threadIdx.x;
  const int n0 = blockIdx.x * 64;
#pragma unroll
  for (int i = 0; i < 4; ++i) {
    int id = i * 512 + tid;
    int r = id >> 5, cq = id & 31;
    int rg = n0 + r; if (rg >= N_NODES) rg = N_NODES - 1;
    float4 v = *(const float4*)(h + (size_t)rg * 128 + cq * 4);
    uint2 s;
    s.x = pack2bf(v.x, v.y);
    s.y = pack2bf(v.z, v.w);
    *(uint2*)(Z + r * 136 + cq * 4) = s;
  }
  __syncthreads();
  const int w = tid >> 6, lane = tid & 63, q = lane >> 4, n = lane & 15;
  const int et = w & 3, cg = w >> 2;
  const int erow = et * 16 + n;
  floatx4 accR[4], accS[4];
#pragma unroll
  for (int cc = 0; cc < 4; ++cc) {
    accR[cc] = (floatx4){0.f, 0.f, 0.f, 0.f};
    accS[cc] = (floatx4){0.f, 0.f, 0.f, 0.f};
  }
  const short* Brow = Z + erow * 136 + q * 8;
  const short8* A = (const short8*)W1f;
#pragma unroll
  for (int kt = 0; kt < 4; ++kt) {
    short8 b = *(const short8*)(Brow + kt * 32);
#pragma unroll
    for (int cc = 0; cc < 4; ++cc) {
      short8 aT = A[kt * 512 + (cg * 4 + cc) * 64 + lane];          // top half
      accR[cc] = __builtin_amdgcn_mfma_f32_16x16x32_bf16(aT, b, accR[cc], 0, 0, 0);
      short8 aB = A[(kt + 4) * 512 + (cg * 4 + cc) * 64 + lane];    // bottom half
      accS[cc] = __builtin_amdgcn_mfma_f32_16x16x32_bf16(aB, b, accS[cc], 0, 0, 0);
    }
  }
  const int node = n0 + erow;
  if (node < N_NODES) {
#pragma unroll
    for (int cc = 0; cc < 4; ++cc) {
      int col = (cg * 4 + cc) * 16 + 4 * q;
      const float4 b1 = *(const float4*)(eb1 + col);
      uint2 ur, us;
      ur.x = pack2bf(accR[cc][0] + b1.x, accR[cc][1] + b1.y);
      ur.y = pack2bf(accR[cc][2] + b1.z, accR[cc][3] + b1.w);
      us.x = pack2bf(accS[cc][0], accS[cc][1]);
      us.y = pack2bf(accS[cc][2], accS[cc][3]);
      *(uint2*)(Rb + (size_t)node * 128 + col) = ur;
      *(uint2*)(Sb + (size_t)node * 128 + col) = us;
    }
  }
}

// ---- CSR build: histogram of destination rows; atomic return = edge's rank
__global__ void hist_kernel(const int* __restrict__ idx, int* __restrict__ cnt,
                            int* __restrict__ rank) {
  int gid = blockIdx.x * 256 + threadIdx.x;
  rank[gid] = atomicAdd(&cnt[idx[gid]], 1);
}

// two-level exclusive scan of cnt[50000] -> ctmp
__global__ void scan1(const int* __restrict__ cnt, int* __restrict__ bsum) {
  const int t = threadIdx.x;
  int i = blockIdx.x * 512 + t;
  int v = (i < N_NODES) ? cnt[i] : 0;
#pragma unroll
  for (int o = 1; o < 64; o <<= 1) v += __shfl_xor(v, o, 64);
  __shared__ int ws_[8];
  if ((t & 63) == 0) ws_[t >> 6] = v;
  __syncthreads();
  if (t == 0) {
    int s = 0;
#pragma unroll
    for (int k = 0; k < 8; ++k) s += ws_[k];
    bsum[blockIdx.x] = s;
  }
}

__global__ void scan2(const int* __restrict__ bsum, int* __restrict__ boff) {
  const int t = threadIdx.x;   // 128 threads
  int v = (t < 98) ? bsum[t] : 0;
  int incl = v;
  const int lane = t & 63;
#pragma unroll
  for (int o = 1; o < 64; o <<= 1) {
    int tmp = __shfl_up(incl, o, 64);
    if (lane >= o) incl += tmp;
  }
  __shared__ int s0;
  if (t == 63) s0 = incl;
  __syncthreads();
  if (t >= 64) incl += s0;
  boff[t] = incl - v;
}

__global__ void scan3(const int* __restrict__ cnt, const int* __restrict__ boff,
                      int* __restrict__ ctmp) {
  const int t = threadIdx.x;
  const int i = blockIdx.x * 512 + t;
  int v = (i < N_NODES) ? cnt[i] : 0;
  int incl = v;
  const int lane = t & 63;
#pragma unroll
  for (int o = 1; o < 64; o <<= 1) {
    int tmp = __shfl_up(incl, o, 64);
    if (lane >= o) incl += tmp;
  }
  __shared__ int wsum[8];
  if (lane == 63) wsum[t >> 6] = incl;
  __syncthreads();
  if (t == 0) {
    int run = 0;
#pragma unroll
    for (int k = 0; k < 8; ++k) { int x = wsum[k]; wsum[k] = run; run += x; }
  }
  __syncthreads();
  if (i < N_NODES) ctmp[i] = incl - v + wsum[t >> 6] + boff[blockIdx.x];
}

// place edges into sorted order: p = row_base + precomputed rank (NO atomics)
__global__ void place_kernel(const int* __restrict__ idx, const int* __restrict__ ctmp,
                             const int* __restrict__ rank, int2* __restrict__ sedge) {
  int gid = blockIdx.x * 256 + threadIdx.x;
  int r = idx[gid];
  int c = idx[N_EDGES + gid];
  int p = ctmp[r] + rank[gid];
  sedge[p] = make_int2(r, c);
}

// Edge kernel: 64 sorted edges/block, 1024 threads (16 waves).
// Wave w: et=w&3 (edge 16-tile), cg=w>>2 in 0..3 (channel QUARTER: chunks
// ct=cg*2+cc, cc in 0..1). Lane(q,n): edge erow=et*16+n, channels ct*16+4q+j.
// Per-lane state halved vs r9 (acc2[2]=8 AGPR, sil[2][4]=8 f32) -> no spills
// under the 64-reg cap at 8 waves/EU (unified VGPR/AGPR file).
__global__ void __launch_bounds__(1024, 8) edge_kernel(
    const short* __restrict__ Rb, const short* __restrict__ Sb,
    const int2* __restrict__ sedge, const short* __restrict__ W2f,
    const float* __restrict__ eb2, const float* __restrict__ aW,
    const float* __restrict__ ab, unsigned short* __restrict__ agg) {
  __shared__ __align__(16) short M1[64 * 136];
  __shared__ float patt[64][4];
  const int tid = threadIdx.x;
  const int e0 = blockIdx.x * 64;
  const int w = tid >> 6, lane = tid & 63, q = lane >> 4, n = lane & 15;
  const int et = w & 3, cg = w >> 2;
  const int erow = et * 16 + n;
  const int2 ed = sedge[e0 + erow];
  const int myrow = ed.x;

  // ---- layer 1 elementwise: m1 = silu(R'[row] + S[col]) for 2 chunks
  {
    const short* Rrow = Rb + (size_t)myrow * 128;
    const short* Srow = Sb + (size_t)ed.y * 128;
#pragma unroll
    for (int cc = 0; cc < 2; ++cc) {
      int off = (cg * 2 + cc) * 16 + 4 * q;
      uint2 ur = *(const uint2*)(Rrow + off);
      uint2 us = *(const uint2*)(Srow + off);
      float v0 = bflo2f(ur.x) + bflo2f(us.x);
      float v1 = bfhi2f(ur.x) + bfhi2f(us.x);
      float v2 = bflo2f(ur.y) + bflo2f(us.y);
      float v3 = bfhi2f(ur.y) + bfhi2f(us.y);
      uint2 u;
      u.x = pack2bf(fsilu(v0), fsilu(v1));
      u.y = pack2bf(fsilu(v2), fsilu(v3));
      *(uint2*)(M1 + erow * 136 + off) = u;
    }
  }
  __syncthreads();

  // ---- layer 2 (transposed): C^T = W2^T @ M1^T, this wave's 2 chunks
  floatx4 acc2[2];
#pragma unroll
  for (int cc = 0; cc < 2; ++cc) acc2[cc] = (floatx4){0.f, 0.f, 0.f, 0.f};
  {
    const short* Brow = M1 + erow * 136 + q * 8;
    const short8* A = (const short8*)W2f;
#pragma unroll
    for (int kt = 0; kt < 4; ++kt) {
      short8 b = *(const short8*)(Brow + kt * 32);
#pragma unroll
      for (int cc = 0; cc < 2; ++cc) {
        short8 a = A[kt * 512 + (cg * 2 + cc) * 64 + lane];
        acc2[cc] = __builtin_amdgcn_mfma_f32_16x16x32_bf16(a, b, acc2[cc], 0, 0, 0);
      }
    }
  }
  // ---- silu + attention partial dot (this wave's 32 channels)
  float sil[2][4];
  float p = 0.f;
#pragma unroll
  for (int cc = 0; cc < 2; ++cc) {
    int ct = cg * 2 + cc;
    const float4 b2 = *(const float4*)(eb2 + ct * 16 + 4 * q);
    const float4 av = *(const float4*)(aW + ct * 16 + 4 * q);
#pragma unroll
    for (int j = 0; j < 4; ++j) {
      float v = fsilu(acc2[cc][j] + ((const float*)&b2)[j]);
      sil[cc][j] = v;
      p += v * ((const float*)&av)[j];
    }
  }
  p += __shfl_xor(p, 16, 64);
  p += __shfl_xor(p, 32, 64);
  if (q == 0) patt[erow][cg] = p;
  __syncthreads();

  float s = patt[erow][0] + patt[erow][1] + patt[erow][2] + patt[erow][3] + ab[0];
  float att = 0.01f * __builtin_amdgcn_rcpf(1.f + __builtin_amdgcn_exp2f(-1.442695041f * s));
#pragma unroll
  for (int cc = 0; cc < 2; ++cc)
#pragma unroll
    for (int j = 0; j < 4; ++j) sil[cc][j] *= att;

  // ---- segmented reduction over sorted-row runs along n (16 edges/tile)
  const int prevrow = __shfl_up(myrow, 1, 64);
  const bool head = (n == 0) || (myrow != prevrow);
  const unsigned long long m = __ballot(head);
  const unsigned long long lower = (lane == 63) ? ~0ull : ((2ull << lane) - 1ull);
  const int headpos = 63 - __builtin_clzll(m & lower);
  const int hd = lane - headpos;
  const bool tail = (n == 15) || (((m >> (lane + 1)) & 1ull) != 0);
#pragma unroll
  for (int d = 1; d < 16; d <<= 1) {
    bool take = (d <= hd);
#pragma unroll
    for (int cc = 0; cc < 2; ++cc)
#pragma unroll
      for (int j = 0; j < 4; ++j) {
        float t = __shfl_up(sil[cc][j], d, 64);
        sil[cc][j] += take ? t : 0.f;
      }
  }
  // ---- run tails flush run totals: 4 pk-bf16 atomics per tail lane
  if (tail) {
    unsigned short* base = agg + (size_t)myrow * 128;
#pragma unroll
    for (int cc = 0; cc < 2; ++cc) {
      int colb = (cg * 2 + cc) * 16 + 4 * q;
      unsigned int u0 = pack2bf(sil[cc][0], sil[cc][1]);
      unsigned int u1 = pack2bf(sil[cc][2], sil[cc][3]);
      asm volatile("global_atomic_pk_add_bf16 %0, %1, off" :: "v"(base + colb), "v"(u0) : "memory");
      asm volatile("global_atomic_pk_add_bf16 %0, %1, off" :: "v"(base + colb + 2), "v"(u1) : "memory");
    }
  }
  asm volatile("s_waitcnt vmcnt(0)" ::: "memory");   // drain untracked asm atomics
}

// Node kernel (transposed, 512 threads): 64 nodes/block, 8 waves.
__global__ void __launch_bounds__(512, 6) node_kernel(
    const float* __restrict__ h, const short* __restrict__ agg,
    const short* __restrict__ N1f, const short* __restrict__ N2f,
    const float* __restrict__ nb1, const float* __restrict__ nb2,
    float* __restrict__ out) {
  __shared__ __align__(16) short Smem[16896];   // Z[64][264] overlaid by M1[64][136]
  const int tid = threadIdx.x;
  const int n0 = blockIdx.x * 64;
#pragma unroll
  for (int i = 0; i < 4; ++i) {
    int id = i * 512 + tid;
    int r = id >> 5, ch = id & 31;
    int rg = n0 + r;
    if (rg >= N_NODES) rg = N_NODES - 1;
    if (ch < 16) {
      const float* hp = h + (size_t)rg * 128 + ch * 8;
      float4 a = *(const float4*)hp;
      float4 b = *(const float4*)(hp + 4);
      uint4 sv;
      sv.x = pack2bf(a.x, a.y);
      sv.y = pack2bf(a.z, a.w);
      sv.z = pack2bf(b.x, b.y);
      sv.w = pack2bf(b.z, b.w);
      *(uint4*)(Smem + r * 264 + ch * 8) = sv;
    } else {
      *(uint4*)(Smem + r * 264 + ch * 8) =
          *(const uint4*)(agg + (size_t)rg * 128 + (ch - 16) * 8);
    }
  }
  __syncthreads();
  const int w = tid >> 6, lane = tid & 63, q = lane >> 4, n = lane & 15;
  const int et = w & 3, cg = w >> 2;
  const int erow = et * 16 + n;

  floatx4 acc[4];
#pragma unroll
  for (int cc = 0; cc < 4; ++cc) acc[cc] = (floatx4){0.f, 0.f, 0.f, 0.f};
  {
    const short* Brow = Smem + erow * 264 + q * 8;
    const short8* A = (const short8*)N1f;
#pragma unroll
    for (int kt = 0; kt < 8; ++kt) {
      short8 b = *(const short8*)(Brow + kt * 32);
#pragma unroll
      for (int cc = 0; cc < 4; ++cc) {
        short8 a = A[kt * 512 + (cg * 4 + cc) * 64 + lane];
        acc[cc] = __builtin_amdgcn_mfma_f32_16x16x32_bf16(a, b, acc[cc], 0, 0, 0);
      }
    }
  }
  unsigned int m1p[4][2];
#pragma unroll
  for (int cc = 0; cc < 4; ++cc) {
    int ct = cg * 4 + cc;
    const float4 b1 = *(const float4*)(nb1 + ct * 16 + 4 * q);
    m1p[cc][0] = pack2bf(fsilu(acc[cc][0] + b1.x), fsilu(acc[cc][1] + b1.y));
    m1p[cc][1] = pack2bf(fsilu(acc[cc][2] + b1.z), fsilu(acc[cc][3] + b1.w));
  }
  __syncthreads();
#pragma unroll
  for (int cc = 0; cc < 4; ++cc) {
    int ct = cg * 4 + cc;
    *(uint2*)(Smem + erow * 136 + ct * 16 + 4 * q) = *(uint2*)m1p[cc];
  }
  __syncthreads();

  floatx4 acc2[4];
#pragma unroll
  for (int cc = 0; cc < 4; ++cc) acc2[cc] = (floatx4){0.f, 0.f, 0.f, 0.f};
  {
    const short* Brow = Smem + erow * 136 + q * 8;
    const short8* A = (const short8*)N2f;
#pragma unroll
    for (int kt = 0; kt < 4; ++kt) {
      short8 b = *(const short8*)(Brow + kt * 32);
#pragma unroll
      for (int cc = 0; cc < 4; ++cc) {
        short8 a = A[kt * 512 + (cg * 4 + cc) * 64 + lane];
        acc2[cc] = __builtin_amdgcn_mfma_f32_16x16x32_bf16(a, b, acc2[cc], 0, 0, 0);
      }
    }
  }
  const int node = n0 + erow;
  if (node < N_NODES) {
#pragma unroll
    for (int cc = 0; cc < 4; ++cc) {
      int col = (cg * 4 + cc) * 16 + 4 * q;
      const float4 b2 = *(const float4*)(nb2 + col);
      const float4 hr = *(const float4*)(h + (size_t)node * 128 + col);
      float4 o;
      o.x = acc2[cc][0] + b2.x + hr.x;
      o.y = acc2[cc][1] + b2.y + hr.y;
      o.z = acc2[cc][2] + b2.z + hr.z;
      o.w = acc2[cc][3] + b2.w + hr.w;
      *(float4*)(out + (size_t)node * 128 + col) = o;
    }
  }
}

extern "C" void kernel_launch(void* const* d_in, const int* in_sizes, int n_in,
                              void* d_out, int out_size, void* d_ws, size_t ws_size,
                              hipStream_t stream) {
  (void)in_sizes; (void)n_in; (void)out_size; (void)ws_size;
  const float* h   = (const float*)d_in[0];
  const int*   idx = (const int*)d_in[1];
  const float* eW1 = (const float*)d_in[2];
  const float* eb1 = (const float*)d_in[3];
  const float* eW2 = (const float*)d_in[4];
  const float* eb2 = (const float*)d_in[5];
  const float* aW  = (const float*)d_in[6];
  const float* ab  = (const float*)d_in[7];
  const float* nW1 = (const float*)d_in[8];
  const float* nb1 = (const float*)d_in[9];
  const float* nW2 = (const float*)d_in[10];
  const float* nb2 = (const float*)d_in[11];
  float* out = (float*)d_out;

  // ws layout
  char* wp = (char*)d_ws;
  unsigned short* agg = (unsigned short*)wp;  wp += (size_t)N_NODES * 128 * 2;  // 12.8 MB
  short* Rb  = (short*)wp;                    wp += (size_t)N_NODES * 128 * 2;  // 12.8 MB
  short* Sb  = (short*)wp;                    wp += (size_t)N_NODES * 128 * 2;  // 12.8 MB
  short* W1f = (short*)wp;                    wp += 32768 * 2;
  short* W2f = (short*)wp;                    wp += 16384 * 2;
  short* N1f = (short*)wp;                    wp += 32768 * 2;
  short* N2f = (short*)wp;                    wp += 16384 * 2;
  int* cnt  = (int*)wp;                       wp += N_NODES * 4;
  int* ctmp = (int*)wp;                       wp += N_NODES * 4;
  int* rank = (int*)wp;                       wp += (size_t)N_EDGES * 4;
  int2* sedge = (int2*)wp;                    wp += (size_t)N_EDGES * 8;
  int* bsum = (int*)wp;                       wp += 128 * 4;
  int* boff = (int*)wp;                       wp += 128 * 4;

  hipMemsetAsync(agg, 0, (size_t)N_NODES * 128 * 2, stream);
  hipMemsetAsync(cnt, 0, N_NODES * 4, stream);
  prep_weights<<<48, 256, 0, stream>>>(eW1, eW2, nW1, nW2, W1f, W2f, N1f, N2f);
  prep_hR<<<(N_NODES + 63) / 64, 512, 0, stream>>>(h, W1f, eb1, Rb, Sb);
  hist_kernel<<<N_EDGES / 256, 256, 0, stream>>>(idx, cnt, rank);
  scan1<<<98, 512, 0, stream>>>(cnt, bsum);
  scan2<<<1, 128, 0, stream>>>(bsum, boff);
  scan3<<<98, 512, 0, stream>>>(cnt, boff, ctmp);
  place_kernel<<<N_EDGES / 256, 256, 0, stream>>>(idx, ctmp, rank, sedge);
  edge_kernel<<<N_EDGES / 64, 1024, 0, stream>>>(Rb, Sb, sedge, W2f,
                                                 eb2, aW, ab, agg);
  node_kernel<<<(N_NODES + 63) / 64, 512, 0, stream>>>(h, (const short*)agg,
                                                       N1f, N2f, nb1, nb2, out);
}